// Round 1
// baseline (1223.904 us; speedup 1.0000x reference)
//
#include <hip/hip_runtime.h>

#define BB 2
#define NN 2048
#define CC 1024
#define HH 16
#define HD 64

typedef __attribute__((ext_vector_type(8))) __bf16 bf16x8;
typedef __attribute__((ext_vector_type(4))) float f32x4;

__device__ inline bf16x8 cvt8(float4 a, float4 b) {
    bf16x8 r;
    r[0] = (__bf16)a.x; r[1] = (__bf16)a.y; r[2] = (__bf16)a.z; r[3] = (__bf16)a.w;
    r[4] = (__bf16)b.x; r[5] = (__bf16)b.y; r[6] = (__bf16)b.z; r[7] = (__bf16)b.w;
    return r;
}

// ---------------- 1. mean partial sums over seq ----------------
// grid (8,16) x 256: idx -> (b,c) over B*C=2048; blockIdx.y = chunk of 128 rows
__global__ __launch_bounds__(256) void k_meanpart(const float* __restrict__ x,
                                                  float* __restrict__ partial) {
    int idx = blockIdx.x * 256 + threadIdx.x;   // 0..2047
    int ch  = blockIdx.y;                        // 0..15
    int b = idx >> 10, c = idx & 1023;
    const float* xp = x + ((size_t)b * NN + (size_t)ch * 128) * CC + c;
    float s = 0.f;
    for (int i = 0; i < 128; ++i) s += xp[(size_t)i * CC];
    partial[ch * 2048 + idx] = s;
}

// ---------------- 2. gates * head-weight coef, scaled inv temps ----------------
// grid 32 blocks (b*16+h) x 64 threads (one wave)
__global__ __launch_bounds__(64) void k_coef(const float* __restrict__ partial,
        const float* __restrict__ gate_w, const float* __restrict__ gate_b,
        const float* __restrict__ dtemp, const float* __restrict__ hwts,
        const float* __restrict__ scale_p,
        float* __restrict__ coef, float* __restrict__ invt) {
    int p = blockIdx.x;
    int b = p >> 4, h = p & 15;
    int lane = threadIdx.x;
    float acc = 0.f;
    for (int c = lane; c < CC; c += 64) {
        float mv = 0.f;
        #pragma unroll
        for (int ch = 0; ch < 16; ++ch) mv += partial[ch * 2048 + b * CC + c];
        acc += (mv * (1.f / (float)NN)) * gate_w[h * CC + c];
    }
    #pragma unroll
    for (int m = 32; m; m >>= 1) acc += __shfl_xor(acc, m);
    if (lane == 0) {
        float g = 1.f / (1.f + __expf(-(acc + gate_b[h])));
        float mx = -1e30f;
        for (int i = 0; i < HH; ++i) mx = fmaxf(mx, hwts[i]);
        float s = 0.f;
        for (int i = 0; i < HH; ++i) s += __expf(hwts[i] - mx);
        float hw = __expf(hwts[h] - mx) / s;
        coef[p] = g * hw;
        if (b == 0) {
            float d = dtemp[h];
            float sp = (d > 20.f) ? d : log1pf(__expf(d));
            invt[h] = scale_p[0] / (sp * 1.0f /*BASE_TEMP*/);
        }
    }
}

// ---------------- 3/5. bf16 MFMA GEMM: C[M][O] = A[M][K] * Bt[O][K]^T ----------------
// 64x64 tile, 4 waves, KT=32, mfma_f32_16x16x32_bf16.
// EPI 0: scatter to q/k/v [B,H,N,HD] bf16.  EPI 1: out[m*1024+o] = acc + bias[o] (fp32)
template <typename TA, int EPI>
__global__ __launch_bounds__(256) void k_gemm(const TA* __restrict__ A,
        const float* __restrict__ Bt, int K,
        __bf16* __restrict__ qo, __bf16* __restrict__ ko, __bf16* __restrict__ vo,
        float* __restrict__ outp, const float* __restrict__ bias) {
    __shared__ __bf16 As[64][56];
    __shared__ __bf16 Bs[64][56];
    int t = threadIdx.x;
    int lane = t & 63, w = t >> 6;
    int row = t >> 2, quad = t & 3;
    int m0 = blockIdx.x * 64, o0 = blockIdx.y * 64;
    f32x4 acc[4] = {};
    for (int k0 = 0; k0 < K; k0 += 32) {
        __syncthreads();
        // stage A tile (64x32)
        if constexpr (sizeof(TA) == 4) {
            const float* ap = (const float*)A + (size_t)(m0 + row) * K + k0 + quad * 8;
            float4 f0 = *(const float4*)ap;
            float4 f1 = *(const float4*)(ap + 4);
            *(bf16x8*)&As[row][quad * 8] = cvt8(f0, f1);
        } else {
            const bf16x8* ap = (const bf16x8*)((const __bf16*)A + (size_t)(m0 + row) * K + k0 + quad * 8);
            *(bf16x8*)&As[row][quad * 8] = *ap;
        }
        // stage B tile (64x32), fp32 -> bf16
        {
            const float* bp = Bt + (size_t)(o0 + row) * K + k0 + quad * 8;
            float4 g0 = *(const float4*)bp;
            float4 g1 = *(const float4*)(bp + 4);
            *(bf16x8*)&Bs[row][quad * 8] = cvt8(g0, g1);
        }
        __syncthreads();
        int fr = lane & 15, kg = lane >> 4;
        bf16x8 av = *(const bf16x8*)&As[w * 16 + fr][kg * 8];
        #pragma unroll
        for (int j = 0; j < 4; ++j) {
            bf16x8 bv = *(const bf16x8*)&Bs[j * 16 + fr][kg * 8];
            acc[j] = __builtin_amdgcn_mfma_f32_16x16x32_bf16(av, bv, acc[j], 0, 0, 0);
        }
    }
    int fr = lane & 15, rg = lane >> 4;
    #pragma unroll
    for (int j = 0; j < 4; ++j) {
        #pragma unroll
        for (int reg = 0; reg < 4; ++reg) {
            int m = m0 + w * 16 + rg * 4 + reg;
            int o = o0 + j * 16 + fr;
            float val = acc[j][reg];
            if constexpr (EPI == 0) {
                int part = o >> 10, f = o & 1023;
                int h = f >> 6, d = f & 63;
                int b = m >> 11, n = m & 2047;
                __bf16* dst = (part == 0) ? qo : (part == 1) ? ko : vo;
                dst[(((size_t)b * HH + h) * NN + n) * HD + d] = (__bf16)val;
            } else {
                outp[(size_t)m * 1024 + o] = val + bias[o];
            }
        }
    }
}

// ---------------- 4. flash attention, fp32 vector ----------------
// grid (N/64, H, B) x 256. 4 lanes per query row (k-split), online softmax.
__global__ __launch_bounds__(256) void k_attn(const __bf16* __restrict__ qb,
        const __bf16* __restrict__ kb, const __bf16* __restrict__ vb,
        __bf16* __restrict__ attno, const float* __restrict__ coef,
        const float* __restrict__ invt) {
    __shared__ float Ks[64][68];
    __shared__ float Vs[64][68];
    int t = threadIdx.x;
    int r = t >> 2, sub = t & 3;
    int qt = blockIdx.x, h = blockIdx.y, b = blockIdx.z;
    int bh = b * HH + h;
    size_t base = (size_t)bh * NN * HD;
    float itv = invt[h];
    float cf = coef[bh];
    float qreg[16];
    {
        const bf16x8* qp = (const bf16x8*)(qb + base + (size_t)(qt * 64 + r) * HD + sub * 16);
        bf16x8 q0 = qp[0], q1 = qp[1];
        #pragma unroll
        for (int j = 0; j < 8; ++j) {
            qreg[j]     = (float)q0[j] * itv;   // fold scale/temp into q
            qreg[8 + j] = (float)q1[j] * itv;
        }
    }
    float o[16];
    #pragma unroll
    for (int i = 0; i < 16; ++i) o[i] = 0.f;
    float mrow = -INFINITY, lrow = 0.f;

    for (int kt = 0; kt < NN / 64; ++kt) {
        __syncthreads();
        {
            const __bf16* kp = kb + base + (size_t)(kt * 64 + r) * HD + sub * 16;
            const __bf16* vp = vb + base + (size_t)(kt * 64 + r) * HD + sub * 16;
            bf16x8 kk0 = ((const bf16x8*)kp)[0], kk1 = ((const bf16x8*)kp)[1];
            bf16x8 vv0 = ((const bf16x8*)vp)[0], vv1 = ((const bf16x8*)vp)[1];
            float* kd = &Ks[r][sub * 16];
            float* vd = &Vs[r][sub * 16];
            #pragma unroll
            for (int j = 0; j < 8; ++j) {
                kd[j] = (float)kk0[j]; kd[8 + j] = (float)kk1[j];
                vd[j] = (float)vv0[j]; vd[8 + j] = (float)vv1[j];
            }
        }
        __syncthreads();

        float pown[16];
        #pragma unroll
        for (int g = 0; g < 4; ++g) {
            #pragma unroll
            for (int mi = 0; mi < 16; ++mi) {
                int mo = g * 16 + mi;
                const float4* kr = (const float4*)&Ks[mo][sub * 16];
                float d = 0.f;
                #pragma unroll
                for (int k4 = 0; k4 < 4; ++k4) {
                    float4 kk = kr[k4];
                    d += qreg[k4 * 4 + 0] * kk.x + qreg[k4 * 4 + 1] * kk.y
                       + qreg[k4 * 4 + 2] * kk.z + qreg[k4 * 4 + 3] * kk.w;
                }
                d += __shfl_xor(d, 1, 4);
                d += __shfl_xor(d, 2, 4);
                if (g == sub) pown[mi] = d;  // lane `sub` owns keys [sub*16, sub*16+16)
            }
        }
        float tm = pown[0];
        #pragma unroll
        for (int i = 1; i < 16; ++i) tm = fmaxf(tm, pown[i]);
        tm = fmaxf(tm, __shfl_xor(tm, 1, 4));
        tm = fmaxf(tm, __shfl_xor(tm, 2, 4));
        float mnew = fmaxf(mrow, tm);
        float alpha = __expf(mrow - mnew);
        float ts = 0.f;
        #pragma unroll
        for (int i = 0; i < 16; ++i) { pown[i] = __expf(pown[i] - mnew); ts += pown[i]; }
        ts += __shfl_xor(ts, 1, 4);
        ts += __shfl_xor(ts, 2, 4);
        lrow = lrow * alpha + ts;
        mrow = mnew;
        #pragma unroll
        for (int i = 0; i < 16; ++i) o[i] *= alpha;
        #pragma unroll
        for (int g = 0; g < 4; ++g) {
            #pragma unroll
            for (int mi = 0; mi < 16; ++mi) {
                float pm = __shfl(pown[mi], g, 4);   // broadcast key (g*16+mi)'s p to all 4 lanes
                const float4* vr = (const float4*)&Vs[g * 16 + mi][sub * 16];
                #pragma unroll
                for (int k4 = 0; k4 < 4; ++k4) {
                    float4 vv = vr[k4];
                    o[k4 * 4 + 0] += pm * vv.x; o[k4 * 4 + 1] += pm * vv.y;
                    o[k4 * 4 + 2] += pm * vv.z; o[k4 * 4 + 3] += pm * vv.w;
                }
            }
        }
    }
    float sc = cf / lrow;  // (softmax/l) * gate * hw
    __bf16* op = attno + ((size_t)b * NN + qt * 64 + r) * (HH * HD) + h * HD + sub * 16;
    bf16x8 r0, r1;
    #pragma unroll
    for (int j = 0; j < 8; ++j) {
        r0[j] = (__bf16)(o[j] * sc);
        r1[j] = (__bf16)(o[8 + j] * sc);
    }
    ((bf16x8*)op)[0] = r0;
    ((bf16x8*)op)[1] = r1;
}

extern "C" void kernel_launch(void* const* d_in, const int* in_sizes, int n_in,
                              void* d_out, int out_size, void* d_ws, size_t ws_size,
                              hipStream_t stream) {
    const float* x      = (const float*)d_in[0];
    const float* scale  = (const float*)d_in[1];
    const float* dtemp  = (const float*)d_in[2];
    const float* gate_w = (const float*)d_in[3];
    const float* gate_b = (const float*)d_in[4];
    const float* qkv_w  = (const float*)d_in[5];
    const float* out_w  = (const float*)d_in[6];
    const float* out_b  = (const float*)d_in[7];
    const float* hwts   = (const float*)d_in[8];

    char* wsb = (char*)d_ws;
    float*  partial = (float*)wsb;                      // 16*2048 f32 = 131072 B
    float*  coefp   = (float*)(wsb + 131072);           // 32 f32
    float*  invtp   = (float*)(wsb + 131072 + 128);     // 16 f32
    __bf16* qbuf    = (__bf16*)(wsb + 131584);          // each 2*16*2048*64 bf16 = 8 MB
    const size_t HSZ = (size_t)BB * HH * NN * HD;
    __bf16* kbuf  = qbuf + HSZ;
    __bf16* vbuf  = kbuf + HSZ;
    __bf16* attno = vbuf + HSZ;                          // [B,N,H*HD] bf16
    // total ws: ~33.7 MB

    k_meanpart<<<dim3(8, 16), 256, 0, stream>>>(x, partial);
    k_coef<<<32, 64, 0, stream>>>(partial, gate_w, gate_b, dtemp, hwts, scale, coefp, invtp);
    k_gemm<float, 0><<<dim3(64, 48), 256, 0, stream>>>(x, qkv_w, CC, qbuf, kbuf, vbuf,
                                                       nullptr, nullptr);
    k_attn<<<dim3(NN / 64, HH, BB), 256, 0, stream>>>(qbuf, kbuf, vbuf, attno, coefp, invtp);
    k_gemm<__bf16, 1><<<dim3(64, 16), 256, 0, stream>>>(attno, out_w, HH * HD,
                                                        nullptr, nullptr, nullptr,
                                                        (float*)d_out, out_b);
}

// Round 2
// 326.164 us; speedup vs baseline: 3.7524x; 3.7524x over previous
//
#include <hip/hip_runtime.h>

#define BB 2
#define NN 2048
#define CC 1024
#define HH 16
#define HD 64

typedef __attribute__((ext_vector_type(8))) __bf16 bf16x8;
typedef __attribute__((ext_vector_type(4))) float f32x4;

__device__ inline bf16x8 cvt8(float4 a, float4 b) {
    bf16x8 r;
    r[0] = (__bf16)a.x; r[1] = (__bf16)a.y; r[2] = (__bf16)a.z; r[3] = (__bf16)a.w;
    r[4] = (__bf16)b.x; r[5] = (__bf16)b.y; r[6] = (__bf16)b.z; r[7] = (__bf16)b.w;
    return r;
}

// ---------------- 1. mean partial sums over seq ----------------
__global__ __launch_bounds__(256) void k_meanpart(const float* __restrict__ x,
                                                  float* __restrict__ partial) {
    int idx = blockIdx.x * 256 + threadIdx.x;   // 0..2047
    int ch  = blockIdx.y;                        // 0..15
    int b = idx >> 10, c = idx & 1023;
    const float* xp = x + ((size_t)b * NN + (size_t)ch * 128) * CC + c;
    float s = 0.f;
    for (int i = 0; i < 128; ++i) s += xp[(size_t)i * CC];
    partial[ch * 2048 + idx] = s;
}

// ---------------- 2. gates * head-weight coef, scaled inv temps ----------------
__global__ __launch_bounds__(64) void k_coef(const float* __restrict__ partial,
        const float* __restrict__ gate_w, const float* __restrict__ gate_b,
        const float* __restrict__ dtemp, const float* __restrict__ hwts,
        const float* __restrict__ scale_p,
        float* __restrict__ coef, float* __restrict__ invt) {
    int p = blockIdx.x;
    int b = p >> 4, h = p & 15;
    int lane = threadIdx.x;
    float acc = 0.f;
    for (int c = lane; c < CC; c += 64) {
        float mv = 0.f;
        #pragma unroll
        for (int ch = 0; ch < 16; ++ch) mv += partial[ch * 2048 + b * CC + c];
        acc += (mv * (1.f / (float)NN)) * gate_w[h * CC + c];
    }
    #pragma unroll
    for (int m = 32; m; m >>= 1) acc += __shfl_xor(acc, m);
    if (lane == 0) {
        float g = 1.f / (1.f + __expf(-(acc + gate_b[h])));
        float mx = -1e30f;
        for (int i = 0; i < HH; ++i) mx = fmaxf(mx, hwts[i]);
        float s = 0.f;
        for (int i = 0; i < HH; ++i) s += __expf(hwts[i] - mx);
        float hw = __expf(hwts[h] - mx) / s;
        coef[p] = g * hw;
        if (b == 0) {
            float d = dtemp[h];
            float sp = (d > 20.f) ? d : log1pf(__expf(d));
            invt[h] = scale_p[0] / (sp * 1.0f /*BASE_TEMP*/);
        }
    }
}

// ---------------- 3/5. bf16 MFMA GEMM: C[M][O] = A[M][K] * Bt[O][K]^T ----------------
template <typename TA, int EPI>
__global__ __launch_bounds__(256) void k_gemm(const TA* __restrict__ A,
        const float* __restrict__ Bt, int K,
        __bf16* __restrict__ qo, __bf16* __restrict__ ko, __bf16* __restrict__ vo,
        float* __restrict__ outp, const float* __restrict__ bias) {
    __shared__ __bf16 As[64][56];
    __shared__ __bf16 Bs[64][56];
    int t = threadIdx.x;
    int lane = t & 63, w = t >> 6;
    int row = t >> 2, quad = t & 3;
    int m0 = blockIdx.x * 64, o0 = blockIdx.y * 64;
    f32x4 acc[4] = {};
    for (int k0 = 0; k0 < K; k0 += 32) {
        __syncthreads();
        if constexpr (sizeof(TA) == 4) {
            const float* ap = (const float*)A + (size_t)(m0 + row) * K + k0 + quad * 8;
            float4 f0 = *(const float4*)ap;
            float4 f1 = *(const float4*)(ap + 4);
            *(bf16x8*)&As[row][quad * 8] = cvt8(f0, f1);
        } else {
            const bf16x8* ap = (const bf16x8*)((const __bf16*)A + (size_t)(m0 + row) * K + k0 + quad * 8);
            *(bf16x8*)&As[row][quad * 8] = *ap;
        }
        {
            const float* bp = Bt + (size_t)(o0 + row) * K + k0 + quad * 8;
            float4 g0 = *(const float4*)bp;
            float4 g1 = *(const float4*)(bp + 4);
            *(bf16x8*)&Bs[row][quad * 8] = cvt8(g0, g1);
        }
        __syncthreads();
        int fr = lane & 15, kg = lane >> 4;
        bf16x8 av = *(const bf16x8*)&As[w * 16 + fr][kg * 8];
        #pragma unroll
        for (int j = 0; j < 4; ++j) {
            bf16x8 bv = *(const bf16x8*)&Bs[j * 16 + fr][kg * 8];
            acc[j] = __builtin_amdgcn_mfma_f32_16x16x32_bf16(av, bv, acc[j], 0, 0, 0);
        }
    }
    int fr = lane & 15, rg = lane >> 4;
    #pragma unroll
    for (int j = 0; j < 4; ++j) {
        #pragma unroll
        for (int reg = 0; reg < 4; ++reg) {
            int m = m0 + w * 16 + rg * 4 + reg;
            int o = o0 + j * 16 + fr;
            float val = acc[j][reg];
            if constexpr (EPI == 0) {
                int part = o >> 10, f = o & 1023;
                int h = f >> 6, d = f & 63;
                int b = m >> 11, n = m & 2047;
                __bf16* dst = (part == 0) ? qo : (part == 1) ? ko : vo;
                dst[(((size_t)b * HH + h) * NN + n) * HD + d] = (__bf16)val;
            } else {
                outp[(size_t)m * 1024 + o] = val + bias[o];
            }
        }
    }
}

// ---------------- 4. flash attention, MFMA ----------------
// grid (N/64, H, B) x 256 (4 waves, 16 q-rows each). KV tile = 64.
__global__ __launch_bounds__(256) void k_attn(const __bf16* __restrict__ qb,
        const __bf16* __restrict__ kb, const __bf16* __restrict__ vb,
        __bf16* __restrict__ attno, const float* __restrict__ coef,
        const float* __restrict__ invt) {
    __shared__ __bf16 Ks[64][72];        // [key][d]
    __shared__ __bf16 Vt[64][72];        // [d][key] (transposed)
    __shared__ __bf16 Ps[4][16][72];     // per-wave P tile [q][key]

    int t = threadIdx.x;
    int w = t >> 6, lane = t & 63;
    int fr = lane & 15, kg = lane >> 4;  // frag row/col, k-group (= C row-group)
    int qt = blockIdx.x, h = blockIdx.y, b = blockIdx.z;
    int bh = b * HH + h;
    size_t base = (size_t)bh * NN * HD;
    float itv = invt[h], cf = coef[bh];

    // Q A-frags held in registers: row = fr, k = kk*32 + kg*8 + j
    int qrow = qt * 64 + w * 16 + fr;
    bf16x8 qfrag0 = *(const bf16x8*)(qb + base + (size_t)qrow * HD + kg * 8);
    bf16x8 qfrag1 = *(const bf16x8*)(qb + base + (size_t)qrow * HD + 32 + kg * 8);

    f32x4 o_acc[4] = {};                 // [d-subtile j2], rows kg*4+reg
    float m_r[4], l_r[4];
    #pragma unroll
    for (int reg = 0; reg < 4; ++reg) { m_r[reg] = -INFINITY; l_r[reg] = 0.f; }

    int srow = t >> 2, sdc = t & 3;      // K staging: row, d-chunk (coalesced)
    int vkey = t & 63, vdc = t >> 6;     // V staging: key per lane (conflict-free LDS writes)

    for (int kt = 0; kt < NN / 64; ++kt) {
        __syncthreads();
        // stage K [key][d]
        {
            const __bf16* kp = kb + base + (size_t)(kt * 64 + srow) * HD + sdc * 16;
            *(bf16x8*)&Ks[srow][sdc * 16]     = ((const bf16x8*)kp)[0];
            *(bf16x8*)&Ks[srow][sdc * 16 + 8] = ((const bf16x8*)kp)[1];
        }
        // stage V transposed [d][key]
        {
            const __bf16* vp = vb + base + (size_t)(kt * 64 + vkey) * HD + vdc * 16;
            bf16x8 v0 = ((const bf16x8*)vp)[0], v1 = ((const bf16x8*)vp)[1];
            #pragma unroll
            for (int i = 0; i < 8; ++i) {
                Vt[vdc * 16 + i][vkey]     = v0[i];
                Vt[vdc * 16 + 8 + i][vkey] = v1[i];
            }
        }
        __syncthreads();

        // S = Q K^T  (C: row q = kg*4+reg, col key = j*16+fr)
        f32x4 s_acc[4] = {};
        #pragma unroll
        for (int kk = 0; kk < 2; ++kk) {
            bf16x8 qf = kk ? qfrag1 : qfrag0;
            #pragma unroll
            for (int j = 0; j < 4; ++j) {
                bf16x8 kf = *(const bf16x8*)&Ks[j * 16 + fr][kk * 32 + kg * 8];
                s_acc[j] = __builtin_amdgcn_mfma_f32_16x16x32_bf16(qf, kf, s_acc[j], 0, 0, 0);
            }
        }

        // online softmax in C layout; reduce across the 16 lanes of group kg
        float p[4][4];
        #pragma unroll
        for (int reg = 0; reg < 4; ++reg) {
            float sv[4];
            #pragma unroll
            for (int j = 0; j < 4; ++j) sv[j] = s_acc[j][reg] * itv;
            float rm = fmaxf(fmaxf(sv[0], sv[1]), fmaxf(sv[2], sv[3]));
            rm = fmaxf(rm, __shfl_xor(rm, 1, 16));
            rm = fmaxf(rm, __shfl_xor(rm, 2, 16));
            rm = fmaxf(rm, __shfl_xor(rm, 4, 16));
            rm = fmaxf(rm, __shfl_xor(rm, 8, 16));
            float mn = fmaxf(m_r[reg], rm);
            float a = __expf(m_r[reg] - mn);
            m_r[reg] = mn;
            float ts = 0.f;
            #pragma unroll
            for (int j = 0; j < 4; ++j) { p[j][reg] = __expf(sv[j] - mn); ts += p[j][reg]; }
            ts += __shfl_xor(ts, 1, 16);
            ts += __shfl_xor(ts, 2, 16);
            ts += __shfl_xor(ts, 4, 16);
            ts += __shfl_xor(ts, 8, 16);
            l_r[reg] = l_r[reg] * a + ts;
            #pragma unroll
            for (int j2 = 0; j2 < 4; ++j2) o_acc[j2][reg] *= a;
        }
        // P -> bf16 -> per-wave LDS (row q = kg*4+reg, col key = j*16+fr)
        #pragma unroll
        for (int reg = 0; reg < 4; ++reg)
            #pragma unroll
            for (int j = 0; j < 4; ++j)
                Ps[w][kg * 4 + reg][j * 16 + fr] = (__bf16)p[j][reg];

        // O += P V   (A = P: row q = fr, k = key; B = Vt[d][key])
        #pragma unroll
        for (int kk = 0; kk < 2; ++kk) {
            bf16x8 pf = *(const bf16x8*)&Ps[w][fr][kk * 32 + kg * 8];
            #pragma unroll
            for (int j2 = 0; j2 < 4; ++j2) {
                bf16x8 vf = *(const bf16x8*)&Vt[j2 * 16 + fr][kk * 32 + kg * 8];
                o_acc[j2] = __builtin_amdgcn_mfma_f32_16x16x32_bf16(pf, vf, o_acc[j2], 0, 0, 0);
            }
        }
    }

    // epilogue: out = o * gate*hw / l -> attno [B,N,H*HD]
    #pragma unroll
    for (int reg = 0; reg < 4; ++reg) {
        int r = qt * 64 + w * 16 + kg * 4 + reg;
        float sc = cf / l_r[reg];
        __bf16* op = attno + ((size_t)b * NN + r) * (HH * HD) + h * HD;
        #pragma unroll
        for (int j2 = 0; j2 < 4; ++j2)
            op[j2 * 16 + fr] = (__bf16)(o_acc[j2][reg] * sc);
    }
}

extern "C" void kernel_launch(void* const* d_in, const int* in_sizes, int n_in,
                              void* d_out, int out_size, void* d_ws, size_t ws_size,
                              hipStream_t stream) {
    const float* x      = (const float*)d_in[0];
    const float* scale  = (const float*)d_in[1];
    const float* dtemp  = (const float*)d_in[2];
    const float* gate_w = (const float*)d_in[3];
    const float* gate_b = (const float*)d_in[4];
    const float* qkv_w  = (const float*)d_in[5];
    const float* out_w  = (const float*)d_in[6];
    const float* out_b  = (const float*)d_in[7];
    const float* hwts   = (const float*)d_in[8];

    char* wsb = (char*)d_ws;
    float*  partial = (float*)wsb;
    float*  coefp   = (float*)(wsb + 131072);
    float*  invtp   = (float*)(wsb + 131072 + 128);
    __bf16* qbuf    = (__bf16*)(wsb + 131584);
    const size_t HSZ = (size_t)BB * HH * NN * HD;
    __bf16* kbuf  = qbuf + HSZ;
    __bf16* vbuf  = kbuf + HSZ;
    __bf16* attno = vbuf + HSZ;

    k_meanpart<<<dim3(8, 16), 256, 0, stream>>>(x, partial);
    k_coef<<<32, 64, 0, stream>>>(partial, gate_w, gate_b, dtemp, hwts, scale, coefp, invtp);
    k_gemm<float, 0><<<dim3(64, 48), 256, 0, stream>>>(x, qkv_w, CC, qbuf, kbuf, vbuf,
                                                       nullptr, nullptr);
    k_attn<<<dim3(NN / 64, HH, BB), 256, 0, stream>>>(qbuf, kbuf, vbuf, attno, coefp, invtp);
    k_gemm<__bf16, 1><<<dim3(64, 16), 256, 0, stream>>>(attno, out_w, HH * HD,
                                                        nullptr, nullptr, nullptr,
                                                        (float*)d_out, out_b);
}